// Round 15
// baseline (186.913 us; speedup 1.0000x reference)
//
#include <hip/hip_runtime.h>

#define NB 128
#define NN 50000
#define NE 300000
#define ND 256
#define NP 8

typedef __attribute__((ext_vector_type(4))) float f32x4;
typedef __attribute__((ext_vector_type(8))) short s16x8;

__device__ __forceinline__ unsigned short bf16rtn(float f) {
    unsigned int u = __float_as_uint(f);
    unsigned int r = (u + 0x7fffu + ((u >> 16) & 1u)) >> 16;
    return (unsigned short)r;
}

__device__ __forceinline__ s16x8 pack8(f32x4 a, f32x4 b) {
    s16x8 v;
    v[0] = (short)bf16rtn(a[0]); v[1] = (short)bf16rtn(a[1]);
    v[2] = (short)bf16rtn(a[2]); v[3] = (short)bf16rtn(a[3]);
    v[4] = (short)bf16rtn(b[0]); v[5] = (short)bf16rtn(b[1]);
    v[6] = (short)bf16rtn(b[2]); v[7] = (short)bf16rtn(b[3]);
    return v;
}

__device__ __forceinline__ float eluf(float x) {
    return x > 0.f ? x : __expf(x) - 1.f;
}

// sum across the 16 lanes of a DPP row (VALU-only butterfly, no LDS).
__device__ __forceinline__ float rowsum16(float x) {
    int t;
    t = __builtin_amdgcn_update_dpp(0, __float_as_int(x), 0x121, 0xf, 0xf, true);
    x += __int_as_float(t);
    t = __builtin_amdgcn_update_dpp(0, __float_as_int(x), 0x122, 0xf, 0xf, true);
    x += __int_as_float(t);
    t = __builtin_amdgcn_update_dpp(0, __float_as_int(x), 0x124, 0xf, 0xf, true);
    x += __int_as_float(t);
    t = __builtin_amdgcn_update_dpp(0, __float_as_int(x), 0x128, 0xf, 0xf, true);
    x += __int_as_float(t);
    return x;
}

// ---- stage a 256x256 bf16 W matrix into LDS in FRAGMENT-MAJOR layout ------
// chunk i (of 8192 x 16B) = [cg(16)][kk(8)][lane(64)]; read back as one
// contiguous 1KB block per (cg,kk) at Wl + cg*8192 + kk*1024 + lane*16 ->
// ZERO bank conflicts (verified R12: SQ_LDS_BANK_CONFLICT = 0).
__device__ __forceinline__ void stage_W(char* Wl, const unsigned short* Wsrc,
                                        int tid, int nthr) {
    for (int i = tid; i < 8192; i += nthr) {
        int cg = i >> 9;
        int kk = (i >> 6) & 7;
        int ln = i & 63;
        const unsigned short* src =
            Wsrc + (size_t)(cg * 16 + (ln & 15)) * ND + kk * 32 + (ln >> 4) * 8;
        *(s16x8*)(Wl + i * 16) = *(const s16x8*)src;
    }
}

// ---------------- segment boundaries + rel_logits zeroing ------------------
__global__ void k_starts(const int* __restrict__ idx, int* __restrict__ starts,
                         float* __restrict__ rel_logits) {
    int n = blockIdx.x * blockDim.x + threadIdx.x;
    if (n >= NN) return;
    rel_logits[n] = 0.f;
    int cur = idx[n];
    int prev = (n == 0) ? -1 : idx[n - 1];
    for (int b2 = prev + 1; b2 <= cur; ++b2) starts[b2] = n;
    if (n == NN - 1)
        for (int b2 = cur + 1; b2 <= NB; ++b2) starts[b2] = NN;
}

// ---------------- dsc[e] = dist[src[e]] prepass ----------------------------
__global__ void k_dsc(const int* __restrict__ eidx, const float* __restrict__ dist,
                      float* __restrict__ dscg) {
    int e = blockIdx.x * blockDim.x + threadIdx.x;
    if (e < NE) dscg[e] = dist[eidx[e]];
}

// ---------------- W_edge f32 -> bf16 --------------------------------------
__global__ void k_wedge_bf16(const float* __restrict__ w, unsigned short* __restrict__ o) {
    int i = (blockIdx.x * 256 + threadIdx.x) * 4;
    f32x4 v = *(const f32x4*)(w + i);
    o[i + 0] = bf16rtn(v[0]); o[i + 1] = bf16rtn(v[1]);
    o[i + 2] = bf16rtn(v[2]); o[i + 3] = bf16rtn(v[3]);
}

// ---------------- W_eff[b] = sum_p sim[b,p] * W_p  (f32 -> bf16) ----------
__global__ __launch_bounds__(256) void k_weff(
    const float* __restrict__ sim, const float* __restrict__ Wp,
    unsigned short* __restrict__ Weff)
{
    int chunk = blockIdx.x * 256 + threadIdx.x;
    int off = chunk * 8;
    float wp[NP][8];
#pragma unroll
    for (int p = 0; p < NP; ++p) {
        const float* src = Wp + (size_t)p * ND * ND + off;
        f32x4 w0 = *(const f32x4*)src;
        f32x4 w1 = *(const f32x4*)(src + 4);
        wp[p][0] = w0[0]; wp[p][1] = w0[1]; wp[p][2] = w0[2]; wp[p][3] = w0[3];
        wp[p][4] = w1[0]; wp[p][5] = w1[1]; wp[p][6] = w1[2]; wp[p][7] = w1[3];
    }
    int b0 = blockIdx.y * 16;
    for (int bb = 0; bb < 16; ++bb) {
        int b = b0 + bb;
        float g[8] = {0.f, 0.f, 0.f, 0.f, 0.f, 0.f, 0.f, 0.f};
#pragma unroll
        for (int p = 0; p < NP; ++p) {
            float s = sim[b * NP + p];
#pragma unroll
            for (int j = 0; j < 8; ++j) g[j] += s * wp[p][j];
        }
        s16x8 v;
#pragma unroll
        for (int j = 0; j < 8; ++j) v[j] = (short)bf16rtn(g[j]);
        *(s16x8*)(Weff + (size_t)b * ND * ND + off) = v;
    }
}

// ---------------- edge kernel: barrier-free, 32-edge tiles -----------------
// grid 256 x 1024 (16 waves, 1 block/CU, W 128KB fragment-major in LDS).
// R15: 32 edges per wave-tile (2 rowgroups) -> W LDS traffic HALVES
// (9.4 -> 4.7 MB/CU) and each ds_read_b128 feeds 2 MFMAs (2 indep acc
// chains). Reg audit ~115 < 128: gather-pipelining removed (R14: neutral),
// dd/dv loaded after cg loop (afr dead there). gw transposed (wave*256+bid)
// so the 2-vs-3-tile waves spread across CUs (per-CU work +-1.5%).
__global__ __launch_bounds__(1024, 4) void k_edges(
    const float* __restrict__ instr, const float* __restrict__ dscg,
    const float* __restrict__ eattrs, const unsigned short* __restrict__ Wbf,
    const float* __restrict__ wrs, const int* __restrict__ ebidx,
    const int* __restrict__ eidx, float* __restrict__ rel_logits)
{
    __shared__ char Wl[131072];

    int tid = threadIdx.x;
    int lane = tid & 63;
    int wave = tid >> 6;      // 0..15
    int l15 = lane & 15;
    int q = lane >> 4;        // 0..3

    stage_W(Wl, Wbf, tid, 1024);
    __syncthreads();

    int gw = wave * 256 + blockIdx.x;         // transposed: 0..4095
    const int NT = NE / 32;                   // 9375 tiles, exact
    for (int t = gw; t < NT; t += 4096) {
        int e0 = t * 32;
        int e4a = e0 + 4 * q;                 // rowgroup 0 output rows
        int e4b = e0 + 16 + 4 * q;            // rowgroup 1 output rows

        // instr row bases for the 8 output rows this lane reduces
        const float* ib0 = instr + (size_t)ebidx[e4a + 0] * ND + l15;
        const float* ib1 = instr + (size_t)ebidx[e4a + 1] * ND + l15;
        const float* ib2 = instr + (size_t)ebidx[e4a + 2] * ND + l15;
        const float* ib3 = instr + (size_t)ebidx[e4a + 3] * ND + l15;
        const float* ib4 = instr + (size_t)ebidx[e4b + 0] * ND + l15;
        const float* ib5 = instr + (size_t)ebidx[e4b + 1] * ND + l15;
        const float* ib6 = instr + (size_t)ebidx[e4b + 2] * ND + l15;
        const float* ib7 = instr + (size_t)ebidx[e4b + 3] * ND + l15;

        // A fragments: rowgroup 0 = rows e0+l15, rowgroup 1 = +16
        const float* ar0 = eattrs + (size_t)(e0 + l15) * ND + q * 8;
        const float* ar1 = ar0 + 16 * ND;
        s16x8 af0[8], af1[8];
#pragma unroll
        for (int kk = 0; kk < 8; ++kk) {
            f32x4 a0 = *(const f32x4*)(ar0 + kk * 32);
            f32x4 a1 = *(const f32x4*)(ar0 + kk * 32 + 4);
            af0[kk] = pack8(a0, a1);
        }
#pragma unroll
        for (int kk = 0; kk < 8; ++kk) {
            f32x4 a0 = *(const f32x4*)(ar1 + kk * 32);
            f32x4 a1 = *(const f32x4*)(ar1 + kk * 32 + 4);
            af1[kk] = pack8(a0, a1);
        }

        float p0 = 0.f, p1 = 0.f, p2 = 0.f, p3 = 0.f;
        float p4 = 0.f, p5 = 0.f, p6 = 0.f, p7 = 0.f;
#pragma unroll 1
        for (int cg = 0; cg < 16; ++cg) {
            f32x4 acc0 = {0.f, 0.f, 0.f, 0.f};
            f32x4 acc1 = {0.f, 0.f, 0.f, 0.f};
            const char* fb = Wl + cg * 8192 + lane * 16;
#pragma unroll
            for (int kk = 0; kk < 8; ++kk) {
                s16x8 bf = *(const s16x8*)(fb + kk * 1024);
                acc0 = __builtin_amdgcn_mfma_f32_16x16x32_bf16(af0[kk], bf, acc0, 0, 0, 0);
                acc1 = __builtin_amdgcn_mfma_f32_16x16x32_bf16(af1[kk], bf, acc1, 0, 0, 0);
            }
            int c = cg * 16;
            float wvc = wrs[c + l15];
            p0 += wvc * eluf(ib0[c] * acc0[0]);
            p1 += wvc * eluf(ib1[c] * acc0[1]);
            p2 += wvc * eluf(ib2[c] * acc0[2]);
            p3 += wvc * eluf(ib3[c] * acc0[3]);
            p4 += wvc * eluf(ib4[c] * acc1[0]);
            p5 += wvc * eluf(ib5[c] * acc1[1]);
            p6 += wvc * eluf(ib6[c] * acc1[2]);
            p7 += wvc * eluf(ib7[c] * acc1[3]);
        }
        p0 = rowsum16(p0); p1 = rowsum16(p1);
        p2 = rowsum16(p2); p3 = rowsum16(p3);
        p4 = rowsum16(p4); p5 = rowsum16(p5);
        p6 = rowsum16(p6); p7 = rowsum16(p7);
        if (l15 == 0) {
            atomicAdd(&rel_logits[eidx[NE + e4a + 0]], dscg[e4a + 0] * p0);
            atomicAdd(&rel_logits[eidx[NE + e4a + 1]], dscg[e4a + 1] * p1);
            atomicAdd(&rel_logits[eidx[NE + e4a + 2]], dscg[e4a + 2] * p2);
            atomicAdd(&rel_logits[eidx[NE + e4a + 3]], dscg[e4a + 3] * p3);
            atomicAdd(&rel_logits[eidx[NE + e4b + 0]], dscg[e4b + 0] * p4);
            atomicAdd(&rel_logits[eidx[NE + e4b + 1]], dscg[e4b + 1] * p5);
            atomicAdd(&rel_logits[eidx[NE + e4b + 2]], dscg[e4b + 2] * p6);
            atomicAdd(&rel_logits[eidx[NE + e4b + 3]], dscg[e4b + 3] * p7);
        }
    }
}

// ---------------- node kernel: 16-node tiles (staging-bound, unchanged) ----
__global__ __launch_bounds__(1024, 4) void k_nodes(
    const float* __restrict__ instr, const unsigned short* __restrict__ Weff,
    const float* __restrict__ attrs, const float* __restrict__ wns,
    const int* __restrict__ starts, float* __restrict__ state_logits)
{
    __shared__ char Wl[131072];

    int b = blockIdx.x >> 1;
    int half = blockIdx.x & 1;
    int s0 = starts[b], s1 = starts[b + 1];
    int nt = (s1 - s0 + 15) >> 4;

    int tid = threadIdx.x;
    int lane = tid & 63;
    int wave = tid >> 6;
    int l15 = lane & 15;
    int q = lane >> 4;

    stage_W(Wl, Weff + (size_t)b * ND * ND, tid, 1024);
    __syncthreads();

    const float* irow = instr + (size_t)b * ND + l15;
    for (int t = half * 16 + wave; t < nt; t += 32) {
        int n0 = s0 + t * 16;
        int arn = n0 + l15;
        bool valid = arn < s1;
        const float* arow = attrs + (size_t)arn * ND + q * 8;
        s16x8 afr[8];
#pragma unroll
        for (int kk = 0; kk < 8; ++kk) {
            f32x4 a0 = {0.f, 0.f, 0.f, 0.f}, a1 = {0.f, 0.f, 0.f, 0.f};
            if (valid) {
                a0 = *(const f32x4*)(arow + kk * 32);
                a1 = *(const f32x4*)(arow + kk * 32 + 4);
            }
            afr[kk] = pack8(a0, a1);
        }

        float p0 = 0.f, p1 = 0.f, p2 = 0.f, p3 = 0.f;
#pragma unroll 1
        for (int cg = 0; cg < 16; ++cg) {
            f32x4 acc = {0.f, 0.f, 0.f, 0.f};
            const char* fb = Wl + cg * 8192 + lane * 16;
#pragma unroll
            for (int kk = 0; kk < 8; ++kk) {
                s16x8 bf = *(const s16x8*)(fb + kk * 1024);
                acc = __builtin_amdgcn_mfma_f32_16x16x32_bf16(afr[kk], bf, acc, 0, 0, 0);
            }
            int c = cg * 16;
            float ivc = irow[c];
            float wvc = wns[c + l15];
            p0 += wvc * eluf(ivc * acc[0]);
            p1 += wvc * eluf(ivc * acc[1]);
            p2 += wvc * eluf(ivc * acc[2]);
            p3 += wvc * eluf(ivc * acc[3]);
        }
        p0 = rowsum16(p0); p1 = rowsum16(p1);
        p2 = rowsum16(p2); p3 = rowsum16(p3);
        if (l15 == 0) {
            int n = n0 + 4 * q;
            if (n + 0 < s1) state_logits[n + 0] = p0;
            if (n + 1 < s1) state_logits[n + 1] = p1;
            if (n + 2 < s1) state_logits[n + 2] = p2;
            if (n + 3 < s1) state_logits[n + 3] = p3;
        }
    }
}

// ---------------- per-graph softmaxes + final mix -------------------------
__global__ __launch_bounds__(256) void k_softmax_mix(
    const float* __restrict__ state_l, const float* __restrict__ rel_l,
    const int* __restrict__ starts, const float* __restrict__ relsim,
    float* __restrict__ out)
{
    __shared__ float wms[4], wmr[4], wss[4], wsr[4];
    int b = blockIdx.x;
    int s0 = starts[b], s1 = starts[b + 1];
    if (s1 <= s0) return;
    int tid = threadIdx.x, lane = tid & 63, wave = tid >> 6;

    float ms = -3.4e38f, mr = -3.4e38f;
    for (int n = s0 + tid; n < s1; n += 256) {
        ms = fmaxf(ms, state_l[n]);
        mr = fmaxf(mr, rel_l[n]);
    }
#pragma unroll
    for (int m = 1; m < 64; m <<= 1) {
        ms = fmaxf(ms, __shfl_xor(ms, m, 64));
        mr = fmaxf(mr, __shfl_xor(mr, m, 64));
    }
    if (lane == 0) { wms[wave] = ms; wmr[wave] = mr; }
    __syncthreads();
    ms = fmaxf(fmaxf(wms[0], wms[1]), fmaxf(wms[2], wms[3]));
    mr = fmaxf(fmaxf(wmr[0], wmr[1]), fmaxf(wmr[2], wmr[3]));

    float ss = 0.f, sr = 0.f;
    for (int n = s0 + tid; n < s1; n += 256) {
        ss += __expf(state_l[n] - ms);
        sr += __expf(rel_l[n] - mr);
    }
#pragma unroll
    for (int m = 1; m < 64; m <<= 1) {
        ss += __shfl_xor(ss, m, 64);
        sr += __shfl_xor(sr, m, 64);
    }
    if (lane == 0) { wss[wave] = ss; wsr[wave] = sr; }
    __syncthreads();
    ss = wss[0] + wss[1] + wss[2] + wss[3];
    sr = wsr[0] + wsr[1] + wsr[2] + wsr[3];

    float rb = relsim[b];
    float iss = 1.f / ss, isr = 1.f / sr;
    for (int n = s0 + tid; n < s1; n += 256) {
        out[n] = rb * __expf(rel_l[n] - mr) * isr
               + (1.f - rb) * __expf(state_l[n] - ms) * iss;
    }
}

extern "C" void kernel_launch(void* const* d_in, const int* in_sizes, int n_in,
                              void* d_out, int out_size, void* d_ws, size_t ws_size,
                              hipStream_t stream) {
    const float* instr  = (const float*)d_in[0];
    const float* dist   = (const float*)d_in[1];
    const float* sim    = (const float*)d_in[2];
    const float* relsim = (const float*)d_in[3];
    const float* nattr  = (const float*)d_in[4];
    const float* eattr  = (const float*)d_in[5];
    const float* Wp     = (const float*)d_in[6];
    const float* We     = (const float*)d_in[7];
    const float* wns    = (const float*)d_in[8];
    const float* wrs    = (const float*)d_in[9];
    const int* nidx     = (const int*)d_in[10];
    const int* ebidx    = (const int*)d_in[11];
    const int* eidx     = (const int*)d_in[12];
    float* out = (float*)d_out;

    char* ws = (char*)d_ws;
    float* rel_logits   = (float*)ws;                      // NN f @ 0
    float* state_logits = rel_logits + NN;                 // NN f @ 200000
    int* starts         = (int*)(ws + 400000);             // B+1 ints
    unsigned short* Wbf = (unsigned short*)(ws + 400640);  // 256*256 bf16
    unsigned short* Weff= (unsigned short*)(ws + 532480);  // 128*256*256 bf16 (16.8MB)
    float* dscg         = (float*)(ws + 17309696);         // NE floats (1.2MB)

    k_wedge_bf16<<<64, 256, 0, stream>>>(We, Wbf);
    k_weff<<<dim3(32, 8), 256, 0, stream>>>(sim, Wp, Weff);
    k_starts<<<(NN + 255) / 256, 256, 0, stream>>>(nidx, starts, rel_logits);
    k_dsc<<<(NE + 255) / 256, 256, 0, stream>>>(eidx, dist, dscg);
    k_edges<<<256, 1024, 0, stream>>>(instr, dscg, eattr, Wbf, wrs,
                                      ebidx, eidx, rel_logits);
    k_nodes<<<256, 1024, 0, stream>>>(instr, Weff, nattr, wns, starts,
                                      state_logits);
    k_softmax_mix<<<NB, 256, 0, stream>>>(state_logits, rel_logits, starts,
                                          relsim, out);
}

// Round 16
// 179.561 us; speedup vs baseline: 1.0409x; 1.0409x over previous
//
#include <hip/hip_runtime.h>

#define NB 128
#define NN 50000
#define NE 300000
#define ND 256
#define NP 8

typedef __attribute__((ext_vector_type(4))) float f32x4;
typedef __attribute__((ext_vector_type(8))) short s16x8;

__device__ __forceinline__ unsigned short bf16rtn(float f) {
    unsigned int u = __float_as_uint(f);
    unsigned int r = (u + 0x7fffu + ((u >> 16) & 1u)) >> 16;
    return (unsigned short)r;
}

__device__ __forceinline__ s16x8 pack8(f32x4 a, f32x4 b) {
    s16x8 v;
    v[0] = (short)bf16rtn(a[0]); v[1] = (short)bf16rtn(a[1]);
    v[2] = (short)bf16rtn(a[2]); v[3] = (short)bf16rtn(a[3]);
    v[4] = (short)bf16rtn(b[0]); v[5] = (short)bf16rtn(b[1]);
    v[6] = (short)bf16rtn(b[2]); v[7] = (short)bf16rtn(b[3]);
    return v;
}

__device__ __forceinline__ float eluf(float x) {
    return x > 0.f ? x : __expf(x) - 1.f;
}

// sum across the 16 lanes of a DPP row (VALU-only butterfly, no LDS).
__device__ __forceinline__ float rowsum16(float x) {
    int t;
    t = __builtin_amdgcn_update_dpp(0, __float_as_int(x), 0x121, 0xf, 0xf, true);
    x += __int_as_float(t);
    t = __builtin_amdgcn_update_dpp(0, __float_as_int(x), 0x122, 0xf, 0xf, true);
    x += __int_as_float(t);
    t = __builtin_amdgcn_update_dpp(0, __float_as_int(x), 0x124, 0xf, 0xf, true);
    x += __int_as_float(t);
    t = __builtin_amdgcn_update_dpp(0, __float_as_int(x), 0x128, 0xf, 0xf, true);
    x += __int_as_float(t);
    return x;
}

// ---- stage ncg column-groups of a 256-col bf16 W matrix into LDS ----------
// fragment-major: chunk i = [cg(ncg)][kk(8)][lane(64)] x 16B; read back as
// contiguous 1KB per (cg,kk) -> ZERO bank conflicts (verified R12).
// cg0 = first column-group (column offset cg0*16 in source).
__device__ __forceinline__ void stage_W(char* Wl, const unsigned short* Wsrc,
                                        int cg0, int ncg, int tid, int nthr) {
    int total = ncg * 512;
    for (int i = tid; i < total; i += nthr) {
        int cg = i >> 9;
        int kk = (i >> 6) & 7;
        int ln = i & 63;
        const unsigned short* src =
            Wsrc + (size_t)((cg0 + cg) * 16 + (ln & 15)) * ND + kk * 32 + (ln >> 4) * 8;
        *(s16x8*)(Wl + i * 16) = *(const s16x8*)src;
    }
}

// ---------------- segment boundaries + rel_logits zeroing ------------------
__global__ void k_starts(const int* __restrict__ idx, int* __restrict__ starts,
                         float* __restrict__ rel_logits) {
    int n = blockIdx.x * blockDim.x + threadIdx.x;
    if (n >= NN) return;
    rel_logits[n] = 0.f;
    int cur = idx[n];
    int prev = (n == 0) ? -1 : idx[n - 1];
    for (int b2 = prev + 1; b2 <= cur; ++b2) starts[b2] = n;
    if (n == NN - 1)
        for (int b2 = cur + 1; b2 <= NB; ++b2) starts[b2] = NN;
}

// ---------------- dsc[e] = dist[src[e]] prepass ----------------------------
__global__ void k_dsc(const int* __restrict__ eidx, const float* __restrict__ dist,
                      float* __restrict__ dscg) {
    int e = blockIdx.x * blockDim.x + threadIdx.x;
    if (e < NE) dscg[e] = dist[eidx[e]];
}

// ---------------- W_edge f32 -> bf16 --------------------------------------
__global__ void k_wedge_bf16(const float* __restrict__ w, unsigned short* __restrict__ o) {
    int i = (blockIdx.x * 256 + threadIdx.x) * 4;
    f32x4 v = *(const f32x4*)(w + i);
    o[i + 0] = bf16rtn(v[0]); o[i + 1] = bf16rtn(v[1]);
    o[i + 2] = bf16rtn(v[2]); o[i + 3] = bf16rtn(v[3]);
}

// ---------------- W_eff[b] = sum_p sim[b,p] * W_p  (f32 -> bf16) ----------
__global__ __launch_bounds__(256) void k_weff(
    const float* __restrict__ sim, const float* __restrict__ Wp,
    unsigned short* __restrict__ Weff)
{
    int chunk = blockIdx.x * 256 + threadIdx.x;
    int off = chunk * 8;
    float wp[NP][8];
#pragma unroll
    for (int p = 0; p < NP; ++p) {
        const float* src = Wp + (size_t)p * ND * ND + off;
        f32x4 w0 = *(const f32x4*)src;
        f32x4 w1 = *(const f32x4*)(src + 4);
        wp[p][0] = w0[0]; wp[p][1] = w0[1]; wp[p][2] = w0[2]; wp[p][3] = w0[3];
        wp[p][4] = w1[0]; wp[p][5] = w1[1]; wp[p][6] = w1[2]; wp[p][7] = w1[3];
    }
    int b0 = blockIdx.y * 16;
    for (int bb = 0; bb < 16; ++bb) {
        int b = b0 + bb;
        float g[8] = {0.f, 0.f, 0.f, 0.f, 0.f, 0.f, 0.f, 0.f};
#pragma unroll
        for (int p = 0; p < NP; ++p) {
            float s = sim[b * NP + p];
#pragma unroll
            for (int j = 0; j < 8; ++j) g[j] += s * wp[p][j];
        }
        s16x8 v;
#pragma unroll
        for (int j = 0; j < 8; ++j) v[j] = (short)bf16rtn(g[j]);
        *(s16x8*)(Weff + (size_t)b * ND * ND + off) = v;
    }
}

// ---------------- edge kernel: column-split, 2 blocks/CU, barrier-free -----
// grid 512 x 512 thr (8 waves). Block pair (bid&1) covers cols [0,128) /
// [128,256) of the SAME 16-edge tile stream; each holds its 64KB W-half in
// LDS (fragment-major, conflict-free) -> 2 blocks co-reside per CU (128KB),
// per-tile W LDS traffic HALVES vs R14, cross-block slip covers HBM/atomic
// latency. Registers at R14's proven level (~75 live, (512,4) cap 128 --
// R15's 32-edge variant spilled at 128-reg cap; this doesn't).
// 2 partial atomics/edge (fire-and-forget, rel_logits zeroed in k_starts).
__global__ __launch_bounds__(512, 4) void k_edges(
    const float* __restrict__ instr, const float* __restrict__ dscg,
    const float* __restrict__ eattrs, const unsigned short* __restrict__ Wbf,
    const float* __restrict__ wrs, const int* __restrict__ ebidx,
    const int* __restrict__ eidx, float* __restrict__ rel_logits)
{
    __shared__ char Wl[65536];

    int tid = threadIdx.x;
    int lane = tid & 63;
    int wave = tid >> 6;      // 0..7
    int l15 = lane & 15;
    int q = lane >> 4;        // 0..3
    int half = blockIdx.x & 1;
    int co = half * 128;      // column offset of this block's W-half

    stage_W(Wl, Wbf, half * 8, 8, tid, 512);
    __syncthreads();

    int gw = (blockIdx.x >> 1) * 8 + wave;    // 0..2047 per half
    const int NT = NE / 16;                   // 18750 tiles, exact
    for (int t = gw; t < NT; t += 2048) {
        int e0 = t * 16;
        int e4 = e0 + 4 * q;
        int eb0 = ebidx[e4 + 0], eb1 = ebidx[e4 + 1];
        int eb2 = ebidx[e4 + 2], eb3 = ebidx[e4 + 3];
        const float* ib0 = instr + (size_t)eb0 * ND + co + l15;
        const float* ib1 = instr + (size_t)eb1 * ND + co + l15;
        const float* ib2 = instr + (size_t)eb2 * ND + co + l15;
        const float* ib3 = instr + (size_t)eb3 * ND + co + l15;

        // A: row e0+l15, full K (kk 0..7), 128B contiguous per row per kk
        const float* arow = eattrs + (size_t)(e0 + l15) * ND + q * 8;
        s16x8 afr[8];
#pragma unroll
        for (int kk = 0; kk < 8; ++kk) {
            f32x4 a0 = *(const f32x4*)(arow + kk * 32);
            f32x4 a1 = *(const f32x4*)(arow + kk * 32 + 4);
            afr[kk] = pack8(a0, a1);
        }

        float p0 = 0.f, p1 = 0.f, p2 = 0.f, p3 = 0.f;
#pragma unroll 1
        for (int cg = 0; cg < 8; ++cg) {
            f32x4 acc = {0.f, 0.f, 0.f, 0.f};
            const char* fb = Wl + cg * 8192 + lane * 16;
#pragma unroll
            for (int kk = 0; kk < 8; ++kk) {
                s16x8 bf = *(const s16x8*)(fb + kk * 1024);
                acc = __builtin_amdgcn_mfma_f32_16x16x32_bf16(afr[kk], bf, acc, 0, 0, 0);
            }
            int c = cg * 16;
            float wvc = wrs[co + c + l15];
            p0 += wvc * eluf(ib0[c] * acc[0]);
            p1 += wvc * eluf(ib1[c] * acc[1]);
            p2 += wvc * eluf(ib2[c] * acc[2]);
            p3 += wvc * eluf(ib3[c] * acc[3]);
        }
        p0 = rowsum16(p0); p1 = rowsum16(p1);
        p2 = rowsum16(p2); p3 = rowsum16(p3);
        if (l15 == 0) {
            atomicAdd(&rel_logits[eidx[NE + e4 + 0]], dscg[e4 + 0] * p0);
            atomicAdd(&rel_logits[eidx[NE + e4 + 1]], dscg[e4 + 1] * p1);
            atomicAdd(&rel_logits[eidx[NE + e4 + 2]], dscg[e4 + 2] * p2);
            atomicAdd(&rel_logits[eidx[NE + e4 + 3]], dscg[e4 + 3] * p3);
        }
    }
}

// ---------------- node kernel: R14 version (16-node tiles, plain store) ----
__global__ __launch_bounds__(1024, 4) void k_nodes(
    const float* __restrict__ instr, const unsigned short* __restrict__ Weff,
    const float* __restrict__ attrs, const float* __restrict__ wns,
    const int* __restrict__ starts, float* __restrict__ state_logits)
{
    __shared__ char Wl[131072];

    int b = blockIdx.x >> 1;
    int half = blockIdx.x & 1;
    int s0 = starts[b], s1 = starts[b + 1];
    int nt = (s1 - s0 + 15) >> 4;

    int tid = threadIdx.x;
    int lane = tid & 63;
    int wave = tid >> 6;
    int l15 = lane & 15;
    int q = lane >> 4;

    stage_W(Wl, Weff + (size_t)b * ND * ND, 0, 16, tid, 1024);
    __syncthreads();

    const float* irow = instr + (size_t)b * ND + l15;
    for (int t = half * 16 + wave; t < nt; t += 32) {
        int n0 = s0 + t * 16;
        int arn = n0 + l15;
        bool valid = arn < s1;
        const float* arow = attrs + (size_t)arn * ND + q * 8;
        s16x8 afr[8];
#pragma unroll
        for (int kk = 0; kk < 8; ++kk) {
            f32x4 a0 = {0.f, 0.f, 0.f, 0.f}, a1 = {0.f, 0.f, 0.f, 0.f};
            if (valid) {
                a0 = *(const f32x4*)(arow + kk * 32);
                a1 = *(const f32x4*)(arow + kk * 32 + 4);
            }
            afr[kk] = pack8(a0, a1);
        }

        float p0 = 0.f, p1 = 0.f, p2 = 0.f, p3 = 0.f;
#pragma unroll 1
        for (int cg = 0; cg < 16; ++cg) {
            f32x4 acc = {0.f, 0.f, 0.f, 0.f};
            const char* fb = Wl + cg * 8192 + lane * 16;
#pragma unroll
            for (int kk = 0; kk < 8; ++kk) {
                s16x8 bf = *(const s16x8*)(fb + kk * 1024);
                acc = __builtin_amdgcn_mfma_f32_16x16x32_bf16(afr[kk], bf, acc, 0, 0, 0);
            }
            int c = cg * 16;
            float ivc = irow[c];
            float wvc = wns[c + l15];
            p0 += wvc * eluf(ivc * acc[0]);
            p1 += wvc * eluf(ivc * acc[1]);
            p2 += wvc * eluf(ivc * acc[2]);
            p3 += wvc * eluf(ivc * acc[3]);
        }
        p0 = rowsum16(p0); p1 = rowsum16(p1);
        p2 = rowsum16(p2); p3 = rowsum16(p3);
        if (l15 == 0) {
            int n = n0 + 4 * q;
            if (n + 0 < s1) state_logits[n + 0] = p0;
            if (n + 1 < s1) state_logits[n + 1] = p1;
            if (n + 2 < s1) state_logits[n + 2] = p2;
            if (n + 3 < s1) state_logits[n + 3] = p3;
        }
    }
}

// ---------------- per-graph softmaxes + final mix -------------------------
__global__ __launch_bounds__(256) void k_softmax_mix(
    const float* __restrict__ state_l, const float* __restrict__ rel_l,
    const int* __restrict__ starts, const float* __restrict__ relsim,
    float* __restrict__ out)
{
    __shared__ float wms[4], wmr[4], wss[4], wsr[4];
    int b = blockIdx.x;
    int s0 = starts[b], s1 = starts[b + 1];
    if (s1 <= s0) return;
    int tid = threadIdx.x, lane = tid & 63, wave = tid >> 6;

    float ms = -3.4e38f, mr = -3.4e38f;
    for (int n = s0 + tid; n < s1; n += 256) {
        ms = fmaxf(ms, state_l[n]);
        mr = fmaxf(mr, rel_l[n]);
    }
#pragma unroll
    for (int m = 1; m < 64; m <<= 1) {
        ms = fmaxf(ms, __shfl_xor(ms, m, 64));
        mr = fmaxf(mr, __shfl_xor(mr, m, 64));
    }
    if (lane == 0) { wms[wave] = ms; wmr[wave] = mr; }
    __syncthreads();
    ms = fmaxf(fmaxf(wms[0], wms[1]), fmaxf(wms[2], wms[3]));
    mr = fmaxf(fmaxf(wmr[0], wmr[1]), fmaxf(wmr[2], wmr[3]));

    float ss = 0.f, sr = 0.f;
    for (int n = s0 + tid; n < s1; n += 256) {
        ss += __expf(state_l[n] - ms);
        sr += __expf(rel_l[n] - mr);
    }
#pragma unroll
    for (int m = 1; m < 64; m <<= 1) {
        ss += __shfl_xor(ss, m, 64);
        sr += __shfl_xor(sr, m, 64);
    }
    if (lane == 0) { wss[wave] = ss; wsr[wave] = sr; }
    __syncthreads();
    ss = wss[0] + wss[1] + wss[2] + wss[3];
    sr = wsr[0] + wsr[1] + wsr[2] + wsr[3];

    float rb = relsim[b];
    float iss = 1.f / ss, isr = 1.f / sr;
    for (int n = s0 + tid; n < s1; n += 256) {
        out[n] = rb * __expf(rel_l[n] - mr) * isr
               + (1.f - rb) * __expf(state_l[n] - ms) * iss;
    }
}

extern "C" void kernel_launch(void* const* d_in, const int* in_sizes, int n_in,
                              void* d_out, int out_size, void* d_ws, size_t ws_size,
                              hipStream_t stream) {
    const float* instr  = (const float*)d_in[0];
    const float* dist   = (const float*)d_in[1];
    const float* sim    = (const float*)d_in[2];
    const float* relsim = (const float*)d_in[3];
    const float* nattr  = (const float*)d_in[4];
    const float* eattr  = (const float*)d_in[5];
    const float* Wp     = (const float*)d_in[6];
    const float* We     = (const float*)d_in[7];
    const float* wns    = (const float*)d_in[8];
    const float* wrs    = (const float*)d_in[9];
    const int* nidx     = (const int*)d_in[10];
    const int* ebidx    = (const int*)d_in[11];
    const int* eidx     = (const int*)d_in[12];
    float* out = (float*)d_out;

    char* ws = (char*)d_ws;
    float* rel_logits   = (float*)ws;                      // NN f @ 0
    float* state_logits = rel_logits + NN;                 // NN f @ 200000
    int* starts         = (int*)(ws + 400000);             // B+1 ints
    unsigned short* Wbf = (unsigned short*)(ws + 400640);  // 256*256 bf16
    unsigned short* Weff= (unsigned short*)(ws + 532480);  // 128*256*256 bf16 (16.8MB)
    float* dscg         = (float*)(ws + 17309696);         // NE floats (1.2MB)

    k_wedge_bf16<<<64, 256, 0, stream>>>(We, Wbf);
    k_weff<<<dim3(32, 8), 256, 0, stream>>>(sim, Wp, Weff);
    k_starts<<<(NN + 255) / 256, 256, 0, stream>>>(nidx, starts, rel_logits);
    k_dsc<<<(NE + 255) / 256, 256, 0, stream>>>(eidx, dist, dscg);
    k_edges<<<512, 512, 0, stream>>>(instr, dscg, eattr, Wbf, wrs,
                                     ebidx, eidx, rel_logits);
    k_nodes<<<256, 1024, 0, stream>>>(instr, Weff, nattr, wns, starts,
                                      state_logits);
    k_softmax_mix<<<NB, 256, 0, stream>>>(state_logits, rel_logits, starts,
                                          relsim, out);
}

// Round 17
// 152.444 us; speedup vs baseline: 1.2261x; 1.1779x over previous
//
#include <hip/hip_runtime.h>

#define NB 128
#define NN 50000
#define NE 300000
#define ND 256
#define NP 8

typedef __attribute__((ext_vector_type(4))) float f32x4;
typedef __attribute__((ext_vector_type(8))) short s16x8;

__device__ __forceinline__ unsigned short bf16rtn(float f) {
    unsigned int u = __float_as_uint(f);
    unsigned int r = (u + 0x7fffu + ((u >> 16) & 1u)) >> 16;
    return (unsigned short)r;
}

// one-instruction packed f32->bf16 (RNE, same rounding as bf16rtn):
// v_cvt_pk_bf16_f32 packs src0 -> low16, src1 -> high16.
__device__ __forceinline__ int cvtpk(float lo, float hi) {
    int r;
    asm("v_cvt_pk_bf16_f32 %0, %1, %2" : "=v"(r) : "v"(lo), "v"(hi));
    return r;
}

// 8x f32 -> s16x8 bf16 fragment: 4 cvt_pk ops (was ~32 VALU ops -> ~450cy
// per tile of VALU saved; R16 post-mortem identified pack8 as the largest
// non-overlappable VALU block in k_edges).
__device__ __forceinline__ s16x8 pack8(f32x4 a, f32x4 b) {
    union { int d[4]; s16x8 v; } u;
    u.d[0] = cvtpk(a[0], a[1]);
    u.d[1] = cvtpk(a[2], a[3]);
    u.d[2] = cvtpk(b[0], b[1]);
    u.d[3] = cvtpk(b[2], b[3]);
    return u.v;
}

__device__ __forceinline__ float eluf(float x) {
    return x > 0.f ? x : __expf(x) - 1.f;
}

// sum across the 16 lanes of a DPP row (VALU-only butterfly, no LDS).
__device__ __forceinline__ float rowsum16(float x) {
    int t;
    t = __builtin_amdgcn_update_dpp(0, __float_as_int(x), 0x121, 0xf, 0xf, true);
    x += __int_as_float(t);
    t = __builtin_amdgcn_update_dpp(0, __float_as_int(x), 0x122, 0xf, 0xf, true);
    x += __int_as_float(t);
    t = __builtin_amdgcn_update_dpp(0, __float_as_int(x), 0x124, 0xf, 0xf, true);
    x += __int_as_float(t);
    t = __builtin_amdgcn_update_dpp(0, __float_as_int(x), 0x128, 0xf, 0xf, true);
    x += __int_as_float(t);
    return x;
}

// ---- stage a 256x256 bf16 W matrix into LDS in FRAGMENT-MAJOR layout ------
// chunk i (of 8192 x 16B) = [cg(16)][kk(8)][lane(64)]; read back as one
// contiguous 1KB block per (cg,kk) -> ZERO bank conflicts (verified R12).
__device__ __forceinline__ void stage_W(char* Wl, const unsigned short* Wsrc,
                                        int tid, int nthr) {
    for (int i = tid; i < 8192; i += nthr) {
        int cg = i >> 9;
        int kk = (i >> 6) & 7;
        int ln = i & 63;
        const unsigned short* src =
            Wsrc + (size_t)(cg * 16 + (ln & 15)) * ND + kk * 32 + (ln >> 4) * 8;
        *(s16x8*)(Wl + i * 16) = *(const s16x8*)src;
    }
}

// ---------------- prep: segment starts + zeroing + dsc gather --------------
// grid covers NE; thread n does dscg[n] (all n<NE) and starts/zero (n<NN).
__global__ void k_starts(const int* __restrict__ idx, int* __restrict__ starts,
                         float* __restrict__ rel_logits,
                         const int* __restrict__ eidx,
                         const float* __restrict__ dist,
                         float* __restrict__ dscg) {
    int n = blockIdx.x * blockDim.x + threadIdx.x;
    if (n < NE) dscg[n] = dist[eidx[n]];
    if (n >= NN) return;
    rel_logits[n] = 0.f;
    int cur = idx[n];
    int prev = (n == 0) ? -1 : idx[n - 1];
    for (int b2 = prev + 1; b2 <= cur; ++b2) starts[b2] = n;
    if (n == NN - 1)
        for (int b2 = cur + 1; b2 <= NB; ++b2) starts[b2] = NN;
}

// ---------------- W_edge f32 -> bf16 --------------------------------------
__global__ void k_wedge_bf16(const float* __restrict__ w, unsigned short* __restrict__ o) {
    int i = (blockIdx.x * 256 + threadIdx.x) * 4;
    f32x4 v = *(const f32x4*)(w + i);
    o[i + 0] = bf16rtn(v[0]); o[i + 1] = bf16rtn(v[1]);
    o[i + 2] = bf16rtn(v[2]); o[i + 3] = bf16rtn(v[3]);
}

// ---------------- W_eff[b] = sum_p sim[b,p] * W_p  (f32 -> bf16) ----------
__global__ __launch_bounds__(256) void k_weff(
    const float* __restrict__ sim, const float* __restrict__ Wp,
    unsigned short* __restrict__ Weff)
{
    int chunk = blockIdx.x * 256 + threadIdx.x;
    int off = chunk * 8;
    float wp[NP][8];
#pragma unroll
    for (int p = 0; p < NP; ++p) {
        const float* src = Wp + (size_t)p * ND * ND + off;
        f32x4 w0 = *(const f32x4*)src;
        f32x4 w1 = *(const f32x4*)(src + 4);
        wp[p][0] = w0[0]; wp[p][1] = w0[1]; wp[p][2] = w0[2]; wp[p][3] = w0[3];
        wp[p][4] = w1[0]; wp[p][5] = w1[1]; wp[p][6] = w1[2]; wp[p][7] = w1[3];
    }
    int b0 = blockIdx.y * 16;
    for (int bb = 0; bb < 16; ++bb) {
        int b = b0 + bb;
        float g[8] = {0.f, 0.f, 0.f, 0.f, 0.f, 0.f, 0.f, 0.f};
#pragma unroll
        for (int p = 0; p < NP; ++p) {
            float s = sim[b * NP + p];
#pragma unroll
            for (int j = 0; j < 8; ++j) g[j] += s * wp[p][j];
        }
        s16x8 v;
#pragma unroll
        for (int j = 0; j < 8; ++j) v[j] = (short)bf16rtn(g[j]);
        *(s16x8*)(Weff + (size_t)b * ND * ND + off) = v;
    }
}

// ---------------- edge kernel: barrier-free per-wave streams (R14) ---------
// grid 256 x 1024 (16 waves, 1 block/CU, W 128KB fragment-major in LDS).
// Each wave independently streams 16-edge tiles across ALL 256 cols.
// cg loop NOT unrolled (R12: full unroll -> spill). pack8 now cvt_pk
// (4 ops vs 32). R16's column-split reverted (doubled eattr HBM reads).
__global__ __launch_bounds__(1024, 4) void k_edges(
    const float* __restrict__ instr, const float* __restrict__ dscg,
    const float* __restrict__ eattrs, const unsigned short* __restrict__ Wbf,
    const float* __restrict__ wrs, const int* __restrict__ ebidx,
    const int* __restrict__ eidx, float* __restrict__ rel_logits)
{
    __shared__ char Wl[131072];

    int tid = threadIdx.x;
    int lane = tid & 63;
    int wave = tid >> 6;      // 0..15
    int l15 = lane & 15;
    int q = lane >> 4;        // 0..3

    stage_W(Wl, Wbf, tid, 1024);
    __syncthreads();

    int gw = blockIdx.x * 16 + wave;          // 0..4095
    const int NT = NE / 16;                   // 18750 tiles, exact
    for (int t = gw; t < NT; t += 4096) {
        int e0 = t * 16;
        int e4 = e0 + 4 * q;
        int eb0 = ebidx[e4 + 0], eb1 = ebidx[e4 + 1];
        int eb2 = ebidx[e4 + 2], eb3 = ebidx[e4 + 3];
        float dv0 = dscg[e4 + 0], dv1 = dscg[e4 + 1];
        float dv2 = dscg[e4 + 2], dv3 = dscg[e4 + 3];
        int dd0 = eidx[NE + e4 + 0], dd1 = eidx[NE + e4 + 1];
        int dd2 = eidx[NE + e4 + 2], dd3 = eidx[NE + e4 + 3];

        const float* ib0 = instr + (size_t)eb0 * ND + l15;
        const float* ib1 = instr + (size_t)eb1 * ND + l15;
        const float* ib2 = instr + (size_t)eb2 * ND + l15;
        const float* ib3 = instr + (size_t)eb3 * ND + l15;

        // A: row e0+l15, k-chunks q*32B + kk*128B (16 rows x 128B per kk)
        const float* arow = eattrs + (size_t)(e0 + l15) * ND + q * 8;
        s16x8 afr[8];
#pragma unroll
        for (int kk = 0; kk < 8; ++kk) {
            f32x4 a0 = *(const f32x4*)(arow + kk * 32);
            f32x4 a1 = *(const f32x4*)(arow + kk * 32 + 4);
            afr[kk] = pack8(a0, a1);
        }

        // prime the gather pipeline (values for cg = 0)
        float nv0 = ib0[0], nv1 = ib1[0], nv2 = ib2[0], nv3 = ib3[0];
        float nw = wrs[l15];

        float p0 = 0.f, p1 = 0.f, p2 = 0.f, p3 = 0.f;
#pragma unroll 1
        for (int cg = 0; cg < 16; ++cg) {
            float v0 = nv0, v1 = nv1, v2 = nv2, v3 = nv3, wvc = nw;
            int cn = (cg + 1 < 16 ? cg + 1 : 15) * 16;
            nv0 = ib0[cn]; nv1 = ib1[cn]; nv2 = ib2[cn]; nv3 = ib3[cn];
            nw = wrs[cn + l15];

            f32x4 acc = {0.f, 0.f, 0.f, 0.f};
            const char* fb = Wl + cg * 8192 + lane * 16;
#pragma unroll
            for (int kk = 0; kk < 8; ++kk) {
                s16x8 bf = *(const s16x8*)(fb + kk * 1024);
                acc = __builtin_amdgcn_mfma_f32_16x16x32_bf16(afr[kk], bf, acc, 0, 0, 0);
            }
            p0 += wvc * eluf(v0 * acc[0]);
            p1 += wvc * eluf(v1 * acc[1]);
            p2 += wvc * eluf(v2 * acc[2]);
            p3 += wvc * eluf(v3 * acc[3]);
        }
        p0 = rowsum16(p0); p1 = rowsum16(p1);
        p2 = rowsum16(p2); p3 = rowsum16(p3);
        if (l15 == 0) {
            atomicAdd(&rel_logits[dd0], dv0 * p0);
            atomicAdd(&rel_logits[dd1], dv1 * p1);
            atomicAdd(&rel_logits[dd2], dv2 * p2);
            atomicAdd(&rel_logits[dd3], dv3 * p3);
        }
    }
}

// ---------------- node kernel: same template per graph (R14) ---------------
__global__ __launch_bounds__(1024, 4) void k_nodes(
    const float* __restrict__ instr, const unsigned short* __restrict__ Weff,
    const float* __restrict__ attrs, const float* __restrict__ wns,
    const int* __restrict__ starts, float* __restrict__ state_logits)
{
    __shared__ char Wl[131072];

    int b = blockIdx.x >> 1;
    int half = blockIdx.x & 1;
    int s0 = starts[b], s1 = starts[b + 1];
    int nt = (s1 - s0 + 15) >> 4;

    int tid = threadIdx.x;
    int lane = tid & 63;
    int wave = tid >> 6;
    int l15 = lane & 15;
    int q = lane >> 4;

    stage_W(Wl, Weff + (size_t)b * ND * ND, tid, 1024);
    __syncthreads();

    const float* irow = instr + (size_t)b * ND + l15;
    for (int t = half * 16 + wave; t < nt; t += 32) {
        int n0 = s0 + t * 16;
        int arn = n0 + l15;
        bool valid = arn < s1;
        const float* arow = attrs + (size_t)arn * ND + q * 8;
        s16x8 afr[8];
#pragma unroll
        for (int kk = 0; kk < 8; ++kk) {
            f32x4 a0 = {0.f, 0.f, 0.f, 0.f}, a1 = {0.f, 0.f, 0.f, 0.f};
            if (valid) {
                a0 = *(const f32x4*)(arow + kk * 32);
                a1 = *(const f32x4*)(arow + kk * 32 + 4);
            }
            afr[kk] = pack8(a0, a1);
        }

        float p0 = 0.f, p1 = 0.f, p2 = 0.f, p3 = 0.f;
#pragma unroll 1
        for (int cg = 0; cg < 16; ++cg) {
            f32x4 acc = {0.f, 0.f, 0.f, 0.f};
            const char* fb = Wl + cg * 8192 + lane * 16;
#pragma unroll
            for (int kk = 0; kk < 8; ++kk) {
                s16x8 bf = *(const s16x8*)(fb + kk * 1024);
                acc = __builtin_amdgcn_mfma_f32_16x16x32_bf16(afr[kk], bf, acc, 0, 0, 0);
            }
            int c = cg * 16;
            float ivc = irow[c];
            float wvc = wns[c + l15];
            p0 += wvc * eluf(ivc * acc[0]);
            p1 += wvc * eluf(ivc * acc[1]);
            p2 += wvc * eluf(ivc * acc[2]);
            p3 += wvc * eluf(ivc * acc[3]);
        }
        p0 = rowsum16(p0); p1 = rowsum16(p1);
        p2 = rowsum16(p2); p3 = rowsum16(p3);
        if (l15 == 0) {
            int n = n0 + 4 * q;
            if (n + 0 < s1) state_logits[n + 0] = p0;
            if (n + 1 < s1) state_logits[n + 1] = p1;
            if (n + 2 < s1) state_logits[n + 2] = p2;
            if (n + 3 < s1) state_logits[n + 3] = p3;
        }
    }
}

// ---------------- per-graph softmaxes + final mix -------------------------
__global__ __launch_bounds__(256) void k_softmax_mix(
    const float* __restrict__ state_l, const float* __restrict__ rel_l,
    const int* __restrict__ starts, const float* __restrict__ relsim,
    float* __restrict__ out)
{
    __shared__ float wms[4], wmr[4], wss[4], wsr[4];
    int b = blockIdx.x;
    int s0 = starts[b], s1 = starts[b + 1];
    if (s1 <= s0) return;
    int tid = threadIdx.x, lane = tid & 63, wave = tid >> 6;

    float ms = -3.4e38f, mr = -3.4e38f;
    for (int n = s0 + tid; n < s1; n += 256) {
        ms = fmaxf(ms, state_l[n]);
        mr = fmaxf(mr, rel_l[n]);
    }
#pragma unroll
    for (int m = 1; m < 64; m <<= 1) {
        ms = fmaxf(ms, __shfl_xor(ms, m, 64));
        mr = fmaxf(mr, __shfl_xor(mr, m, 64));
    }
    if (lane == 0) { wms[wave] = ms; wmr[wave] = mr; }
    __syncthreads();
    ms = fmaxf(fmaxf(wms[0], wms[1]), fmaxf(wms[2], wms[3]));
    mr = fmaxf(fmaxf(wmr[0], wmr[1]), fmaxf(wmr[2], wmr[3]));

    float ss = 0.f, sr = 0.f;
    for (int n = s0 + tid; n < s1; n += 256) {
        ss += __expf(state_l[n] - ms);
        sr += __expf(rel_l[n] - mr);
    }
#pragma unroll
    for (int m = 1; m < 64; m <<= 1) {
        ss += __shfl_xor(ss, m, 64);
        sr += __shfl_xor(sr, m, 64);
    }
    if (lane == 0) { wss[wave] = ss; wsr[wave] = sr; }
    __syncthreads();
    ss = wss[0] + wss[1] + wss[2] + wss[3];
    sr = wsr[0] + wsr[1] + wsr[2] + wsr[3];

    float rb = relsim[b];
    float iss = 1.f / ss, isr = 1.f / sr;
    for (int n = s0 + tid; n < s1; n += 256) {
        out[n] = rb * __expf(rel_l[n] - mr) * isr
               + (1.f - rb) * __expf(state_l[n] - ms) * iss;
    }
}

extern "C" void kernel_launch(void* const* d_in, const int* in_sizes, int n_in,
                              void* d_out, int out_size, void* d_ws, size_t ws_size,
                              hipStream_t stream) {
    const float* instr  = (const float*)d_in[0];
    const float* dist   = (const float*)d_in[1];
    const float* sim    = (const float*)d_in[2];
    const float* relsim = (const float*)d_in[3];
    const float* nattr  = (const float*)d_in[4];
    const float* eattr  = (const float*)d_in[5];
    const float* Wp     = (const float*)d_in[6];
    const float* We     = (const float*)d_in[7];
    const float* wns    = (const float*)d_in[8];
    const float* wrs    = (const float*)d_in[9];
    const int* nidx     = (const int*)d_in[10];
    const int* ebidx    = (const int*)d_in[11];
    const int* eidx     = (const int*)d_in[12];
    float* out = (float*)d_out;

    char* ws = (char*)d_ws;
    float* rel_logits   = (float*)ws;                      // NN f @ 0
    float* state_logits = rel_logits + NN;                 // NN f @ 200000
    int* starts         = (int*)(ws + 400000);             // B+1 ints
    unsigned short* Wbf = (unsigned short*)(ws + 400640);  // 256*256 bf16
    unsigned short* Weff= (unsigned short*)(ws + 532480);  // 128*256*256 bf16 (16.8MB)
    float* dscg         = (float*)(ws + 17309696);         // NE floats (1.2MB)

    k_wedge_bf16<<<64, 256, 0, stream>>>(We, Wbf);
    k_weff<<<dim3(32, 8), 256, 0, stream>>>(sim, Wp, Weff);
    k_starts<<<(NE + 255) / 256, 256, 0, stream>>>(nidx, starts, rel_logits,
                                                   eidx, dist, dscg);
    k_edges<<<256, 1024, 0, stream>>>(instr, dscg, eattr, Wbf, wrs,
                                      ebidx, eidx, rel_logits);
    k_nodes<<<256, 1024, 0, stream>>>(instr, Weff, nattr, wns, starts,
                                      state_logits);
    k_softmax_mix<<<NB, 256, 0, stream>>>(state_logits, rel_logits, starts,
                                          relsim, out);
}

// Round 18
// 129.317 us; speedup vs baseline: 1.4454x; 1.1788x over previous
//
#include <hip/hip_runtime.h>

#define NB 128
#define NN 50000
#define NE 300000
#define ND 256
#define NP 8

typedef __attribute__((ext_vector_type(4))) float f32x4;
typedef __attribute__((ext_vector_type(8))) short s16x8;

__device__ __forceinline__ unsigned short bf16rtn(float f) {
    unsigned int u = __float_as_uint(f);
    unsigned int r = (u + 0x7fffu + ((u >> 16) & 1u)) >> 16;
    return (unsigned short)r;
}

// one-instruction packed f32->bf16 (RNE, same rounding as bf16rtn)
__device__ __forceinline__ int cvtpk(float lo, float hi) {
    int r;
    asm("v_cvt_pk_bf16_f32 %0, %1, %2" : "=v"(r) : "v"(lo), "v"(hi));
    return r;
}

__device__ __forceinline__ s16x8 pack8(f32x4 a, f32x4 b) {
    union { int d[4]; s16x8 v; } u;
    u.d[0] = cvtpk(a[0], a[1]);
    u.d[1] = cvtpk(a[2], a[3]);
    u.d[2] = cvtpk(b[0], b[1]);
    u.d[3] = cvtpk(b[2], b[3]);
    return u.v;
}

__device__ __forceinline__ float eluf(float x) {
    return x > 0.f ? x : __expf(x) - 1.f;
}

// sum across the 16 lanes of a DPP row (VALU-only butterfly, no LDS).
__device__ __forceinline__ float rowsum16(float x) {
    int t;
    t = __builtin_amdgcn_update_dpp(0, __float_as_int(x), 0x121, 0xf, 0xf, true);
    x += __int_as_float(t);
    t = __builtin_amdgcn_update_dpp(0, __float_as_int(x), 0x122, 0xf, 0xf, true);
    x += __int_as_float(t);
    t = __builtin_amdgcn_update_dpp(0, __float_as_int(x), 0x124, 0xf, 0xf, true);
    x += __int_as_float(t);
    t = __builtin_amdgcn_update_dpp(0, __float_as_int(x), 0x128, 0xf, 0xf, true);
    x += __int_as_float(t);
    return x;
}

// ---- stage a 256x256 bf16 W matrix into LDS in FRAGMENT-MAJOR layout ------
// chunk i = [cg(16)][kk(8)][lane(64)] x 16B; read back contiguous 1KB per
// (cg,kk) -> ZERO bank conflicts (verified R12).
__device__ __forceinline__ void stage_W(char* Wl, const unsigned short* Wsrc,
                                        int tid, int nthr) {
    for (int i = tid; i < 8192; i += nthr) {
        int cg = i >> 9;
        int kk = (i >> 6) & 7;
        int ln = i & 63;
        const unsigned short* src =
            Wsrc + (size_t)(cg * 16 + (ln & 15)) * ND + kk * 32 + (ln >> 4) * 8;
        *(s16x8*)(Wl + i * 16) = *(const s16x8*)src;
    }
}

// ---------------- fused prep kernel ----------------------------------------
// bid 0..63: W_edge f32->bf16 | 64..319: W_eff combine | 320+: starts/zero/dsc
__global__ __launch_bounds__(256) void k_prep(
    const float* __restrict__ We, unsigned short* __restrict__ Wbf,
    const float* __restrict__ sim, const float* __restrict__ Wp,
    unsigned short* __restrict__ Weff,
    const int* __restrict__ nidx, int* __restrict__ starts,
    float* __restrict__ rel_logits,
    const int* __restrict__ eidx, const float* __restrict__ dist,
    float* __restrict__ dscg)
{
    int bid = blockIdx.x;
    int tid = threadIdx.x;
    if (bid < 64) {
        int i = (bid * 256 + tid) * 4;
        f32x4 v = *(const f32x4*)(We + i);
        Wbf[i + 0] = bf16rtn(v[0]); Wbf[i + 1] = bf16rtn(v[1]);
        Wbf[i + 2] = bf16rtn(v[2]); Wbf[i + 3] = bf16rtn(v[3]);
    } else if (bid < 320) {
        int wb = bid - 64;
        int chunk = (wb & 31) * 256 + tid;
        int off = chunk * 8;
        float wp[NP][8];
#pragma unroll
        for (int p = 0; p < NP; ++p) {
            const float* src = Wp + (size_t)p * ND * ND + off;
            f32x4 w0 = *(const f32x4*)src;
            f32x4 w1 = *(const f32x4*)(src + 4);
            wp[p][0] = w0[0]; wp[p][1] = w0[1]; wp[p][2] = w0[2]; wp[p][3] = w0[3];
            wp[p][4] = w1[0]; wp[p][5] = w1[1]; wp[p][6] = w1[2]; wp[p][7] = w1[3];
        }
        int b0 = (wb >> 5) * 16;
        for (int bb = 0; bb < 16; ++bb) {
            int b = b0 + bb;
            float g[8] = {0.f, 0.f, 0.f, 0.f, 0.f, 0.f, 0.f, 0.f};
#pragma unroll
            for (int p = 0; p < NP; ++p) {
                float s = sim[b * NP + p];
#pragma unroll
                for (int j = 0; j < 8; ++j) g[j] += s * wp[p][j];
            }
            s16x8 v;
#pragma unroll
            for (int j = 0; j < 8; ++j) v[j] = (short)bf16rtn(g[j]);
            *(s16x8*)(Weff + (size_t)b * ND * ND + off) = v;
        }
    } else {
        int n = (bid - 320) * 256 + tid;
        if (n < NE) dscg[n] = dist[eidx[n]];
        if (n >= NN) return;
        rel_logits[n] = 0.f;
        int cur = nidx[n];
        int prev = (n == 0) ? -1 : nidx[n - 1];
        for (int b2 = prev + 1; b2 <= cur; ++b2) starts[b2] = n;
        if (n == NN - 1)
            for (int b2 = cur + 1; b2 <= NB; ++b2) starts[b2] = NN;
    }
}

// ---------------- fused main kernel: edges (bid<256) + nodes (bid>=256) ----
// Edges blocks dispatch first (long pole, 1 block/CU at 128KB LDS); CUs that
// finish backfill with nodes blocks -> k_nodes + edge-tail overlap.
// Edges: barrier-free per-wave 16-edge tile streams, W fragment-major in LDS
// (0 bank conflicts), cg loop unroll 1 (R12: full unroll spills).
// gw = wave*256+bid BALANCED (R14's bid*16+wave put all 5-tile waves on
// blocks 0-147 -> 25% CU imbalance; now each block has ~9 heavy/7 light).
// s_setprio(1) around MFMA cluster (m191: helps independent-wave kernels).
__global__ __launch_bounds__(1024, 4) void k_main(
    const float* __restrict__ instr, const float* __restrict__ dscg,
    const float* __restrict__ eattrs, const unsigned short* __restrict__ Wbf,
    const float* __restrict__ wrs, const int* __restrict__ ebidx,
    const int* __restrict__ eidx, float* __restrict__ rel_logits,
    const unsigned short* __restrict__ Weff, const float* __restrict__ nattrs,
    const float* __restrict__ wns, const int* __restrict__ starts,
    float* __restrict__ state_logits)
{
    __shared__ char Wl[131072];

    int tid = threadIdx.x;
    int lane = tid & 63;
    int wave = tid >> 6;      // 0..15
    int l15 = lane & 15;
    int q = lane >> 4;        // 0..3

    if (blockIdx.x < 256) {
        // ================= EDGES =================
        stage_W(Wl, Wbf, tid, 1024);
        __syncthreads();

        int gw = wave * 256 + blockIdx.x;         // balanced heavy/light mix
        const int NT = NE / 16;                   // 18750
        for (int t = gw; t < NT; t += 4096) {
            int e0 = t * 16;
            int e4 = e0 + 4 * q;
            int eb0 = ebidx[e4 + 0], eb1 = ebidx[e4 + 1];
            int eb2 = ebidx[e4 + 2], eb3 = ebidx[e4 + 3];
            float dv0 = dscg[e4 + 0], dv1 = dscg[e4 + 1];
            float dv2 = dscg[e4 + 2], dv3 = dscg[e4 + 3];
            int dd0 = eidx[NE + e4 + 0], dd1 = eidx[NE + e4 + 1];
            int dd2 = eidx[NE + e4 + 2], dd3 = eidx[NE + e4 + 3];

            const float* ib0 = instr + (size_t)eb0 * ND + l15;
            const float* ib1 = instr + (size_t)eb1 * ND + l15;
            const float* ib2 = instr + (size_t)eb2 * ND + l15;
            const float* ib3 = instr + (size_t)eb3 * ND + l15;

            const float* arow = eattrs + (size_t)(e0 + l15) * ND + q * 8;
            s16x8 afr[8];
#pragma unroll
            for (int kk = 0; kk < 8; ++kk) {
                f32x4 a0 = *(const f32x4*)(arow + kk * 32);
                f32x4 a1 = *(const f32x4*)(arow + kk * 32 + 4);
                afr[kk] = pack8(a0, a1);
            }

            float nv0 = ib0[0], nv1 = ib1[0], nv2 = ib2[0], nv3 = ib3[0];
            float nw = wrs[l15];

            float p0 = 0.f, p1 = 0.f, p2 = 0.f, p3 = 0.f;
#pragma unroll 1
            for (int cg = 0; cg < 16; ++cg) {
                float v0 = nv0, v1 = nv1, v2 = nv2, v3 = nv3, wvc = nw;
                int cn = (cg + 1 < 16 ? cg + 1 : 15) * 16;
                nv0 = ib0[cn]; nv1 = ib1[cn]; nv2 = ib2[cn]; nv3 = ib3[cn];
                nw = wrs[cn + l15];

                f32x4 acc = {0.f, 0.f, 0.f, 0.f};
                const char* fb = Wl + cg * 8192 + lane * 16;
                __builtin_amdgcn_s_setprio(1);
#pragma unroll
                for (int kk = 0; kk < 8; ++kk) {
                    s16x8 bf = *(const s16x8*)(fb + kk * 1024);
                    acc = __builtin_amdgcn_mfma_f32_16x16x32_bf16(afr[kk], bf, acc, 0, 0, 0);
                }
                __builtin_amdgcn_s_setprio(0);
                p0 += wvc * eluf(v0 * acc[0]);
                p1 += wvc * eluf(v1 * acc[1]);
                p2 += wvc * eluf(v2 * acc[2]);
                p3 += wvc * eluf(v3 * acc[3]);
            }
            p0 = rowsum16(p0); p1 = rowsum16(p1);
            p2 = rowsum16(p2); p3 = rowsum16(p3);
            if (l15 == 0) {
                atomicAdd(&rel_logits[dd0], dv0 * p0);
                atomicAdd(&rel_logits[dd1], dv1 * p1);
                atomicAdd(&rel_logits[dd2], dv2 * p2);
                atomicAdd(&rel_logits[dd3], dv3 * p3);
            }
        }
    } else {
        // ================= NODES =================
        int nb = blockIdx.x - 256;
        int b = nb >> 1;
        int half = nb & 1;
        int s0 = starts[b], s1 = starts[b + 1];
        int nt = (s1 - s0 + 15) >> 4;

        stage_W(Wl, Weff + (size_t)b * ND * ND, tid, 1024);
        __syncthreads();

        const float* irow = instr + (size_t)b * ND + l15;
        for (int t = half * 16 + wave; t < nt; t += 32) {
            int n0 = s0 + t * 16;
            int arn = n0 + l15;
            bool valid = arn < s1;
            const float* arow = nattrs + (size_t)arn * ND + q * 8;
            s16x8 afr[8];
#pragma unroll
            for (int kk = 0; kk < 8; ++kk) {
                f32x4 a0 = {0.f, 0.f, 0.f, 0.f}, a1 = {0.f, 0.f, 0.f, 0.f};
                if (valid) {
                    a0 = *(const f32x4*)(arow + kk * 32);
                    a1 = *(const f32x4*)(arow + kk * 32 + 4);
                }
                afr[kk] = pack8(a0, a1);
            }

            float p0 = 0.f, p1 = 0.f, p2 = 0.f, p3 = 0.f;
#pragma unroll 1
            for (int cg = 0; cg < 16; ++cg) {
                f32x4 acc = {0.f, 0.f, 0.f, 0.f};
                const char* fb = Wl + cg * 8192 + lane * 16;
                __builtin_amdgcn_s_setprio(1);
#pragma unroll
                for (int kk = 0; kk < 8; ++kk) {
                    s16x8 bf = *(const s16x8*)(fb + kk * 1024);
                    acc = __builtin_amdgcn_mfma_f32_16x16x32_bf16(afr[kk], bf, acc, 0, 0, 0);
                }
                __builtin_amdgcn_s_setprio(0);
                int c = cg * 16;
                float ivc = irow[c];
                float wvc = wns[c + l15];
                p0 += wvc * eluf(ivc * acc[0]);
                p1 += wvc * eluf(ivc * acc[1]);
                p2 += wvc * eluf(ivc * acc[2]);
                p3 += wvc * eluf(ivc * acc[3]);
            }
            p0 = rowsum16(p0); p1 = rowsum16(p1);
            p2 = rowsum16(p2); p3 = rowsum16(p3);
            if (l15 == 0) {
                int n = n0 + 4 * q;
                if (n + 0 < s1) state_logits[n + 0] = p0;
                if (n + 1 < s1) state_logits[n + 1] = p1;
                if (n + 2 < s1) state_logits[n + 2] = p2;
                if (n + 3 < s1) state_logits[n + 3] = p3;
            }
        }
    }
}

// ---------------- per-graph softmaxes + final mix -------------------------
__global__ __launch_bounds__(256) void k_softmax_mix(
    const float* __restrict__ state_l, const float* __restrict__ rel_l,
    const int* __restrict__ starts, const float* __restrict__ relsim,
    float* __restrict__ out)
{
    __shared__ float wms[4], wmr[4], wss[4], wsr[4];
    int b = blockIdx.x;
    int s0 = starts[b], s1 = starts[b + 1];
    if (s1 <= s0) return;
    int tid = threadIdx.x, lane = tid & 63, wave = tid >> 6;

    float ms = -3.4e38f, mr = -3.4e38f;
    for (int n = s0 + tid; n < s1; n += 256) {
        ms = fmaxf(ms, state_l[n]);
        mr = fmaxf(mr, rel_l[n]);
    }
#pragma unroll
    for (int m = 1; m < 64; m <<= 1) {
        ms = fmaxf(ms, __shfl_xor(ms, m, 64));
        mr = fmaxf(mr, __shfl_xor(mr, m, 64));
    }
    if (lane == 0) { wms[wave] = ms; wmr[wave] = mr; }
    __syncthreads();
    ms = fmaxf(fmaxf(wms[0], wms[1]), fmaxf(wms[2], wms[3]));
    mr = fmaxf(fmaxf(wmr[0], wmr[1]), fmaxf(wmr[2], wmr[3]));

    float ss = 0.f, sr = 0.f;
    for (int n = s0 + tid; n < s1; n += 256) {
        ss += __expf(state_l[n] - ms);
        sr += __expf(rel_l[n] - mr);
    }
#pragma unroll
    for (int m = 1; m < 64; m <<= 1) {
        ss += __shfl_xor(ss, m, 64);
        sr += __shfl_xor(sr, m, 64);
    }
    if (lane == 0) { wss[wave] = ss; wsr[wave] = sr; }
    __syncthreads();
    ss = wss[0] + wss[1] + wss[2] + wss[3];
    sr = wsr[0] + wsr[1] + wsr[2] + wsr[3];

    float rb = relsim[b];
    float iss = 1.f / ss, isr = 1.f / sr;
    for (int n = s0 + tid; n < s1; n += 256) {
        out[n] = rb * __expf(rel_l[n] - mr) * isr
               + (1.f - rb) * __expf(state_l[n] - ms) * iss;
    }
}

extern "C" void kernel_launch(void* const* d_in, const int* in_sizes, int n_in,
                              void* d_out, int out_size, void* d_ws, size_t ws_size,
                              hipStream_t stream) {
    const float* instr  = (const float*)d_in[0];
    const float* dist   = (const float*)d_in[1];
    const float* sim    = (const float*)d_in[2];
    const float* relsim = (const float*)d_in[3];
    const float* nattr  = (const float*)d_in[4];
    const float* eattr  = (const float*)d_in[5];
    const float* Wp     = (const float*)d_in[6];
    const float* We     = (const float*)d_in[7];
    const float* wns    = (const float*)d_in[8];
    const float* wrs    = (const float*)d_in[9];
    const int* nidx     = (const int*)d_in[10];
    const int* ebidx    = (const int*)d_in[11];
    const int* eidx     = (const int*)d_in[12];
    float* out = (float*)d_out;

    char* ws = (char*)d_ws;
    float* rel_logits   = (float*)ws;                      // NN f @ 0
    float* state_logits = rel_logits + NN;                 // NN f @ 200000
    int* starts         = (int*)(ws + 400000);             // B+1 ints
    unsigned short* Wbf = (unsigned short*)(ws + 400640);  // 256*256 bf16
    unsigned short* Weff= (unsigned short*)(ws + 532480);  // 128*256*256 bf16 (16.8MB)
    float* dscg         = (float*)(ws + 17309696);         // NE floats (1.2MB)

    k_prep<<<320 + (NE + 255) / 256, 256, 0, stream>>>(
        We, Wbf, sim, Wp, Weff, nidx, starts, rel_logits, eidx, dist, dscg);
    k_main<<<512, 1024, 0, stream>>>(instr, dscg, eattr, Wbf, wrs, ebidx, eidx,
                                     rel_logits, Weff, nattr, wns, starts,
                                     state_logits);
    k_softmax_mix<<<NB, 256, 0, stream>>>(state_logits, rel_logits, starts,
                                          relsim, out);
}